// Round 8
// baseline (53.335 us; speedup 1.0000x reference)
//
#include <hip/hip_runtime.h>

// center_loss: loss = (1/N) * sum_i ||feature[i] - center_vector[label[i]]||_2
// N=65536, D=512, C=10000, fp32 in/out.
//
// Structure: one wave per 8 consecutive samples (blocked). 64 lanes x 8 floats
// = 512 = D, coalesced float4 x2 per row. Labels prefetched wave-uniform
// (contiguous -> s_load). 2-deep load pipeline across samples. Reduction
// deferred: 8 independent 6-step shuffle butterflies, interleaved.
// Feature streamed with non-temporal loads (no reuse); centers cached.

typedef float f32x4 __attribute__((ext_vector_type(4)));

#define N_SAMPLES 65536
#define DIM 512
#define F4_PER_ROW (DIM / 4)
#define GRID_BLOCKS 2048
#define BLOCK_THREADS 256
#define WAVES_PER_BLOCK 4
#define TOTAL_WAVES (GRID_BLOCKS * WAVES_PER_BLOCK)   // 8192
#define SPW (N_SAMPLES / TOTAL_WAVES)                 // 8 samples per wave

__global__ __launch_bounds__(BLOCK_THREADS) void center_loss_pass1(
    const float* __restrict__ feature,
    const int* __restrict__ label,
    const float* __restrict__ center,
    float* __restrict__ partial) {
    __shared__ float wsum[WAVES_PER_BLOCK];

    const int wave = threadIdx.x >> 6;
    const int lane = threadIdx.x & 63;
    const int gw = blockIdx.x * WAVES_PER_BLOCK + wave;  // 0..8191
    const int s0 = gw * SPW;

    // --- prefetch labels (wave-uniform, contiguous -> scalar loads) ---
    int labs[SPW];
    const int* lp = label + s0;
    #pragma unroll
    for (int k = 0; k < SPW; ++k) labs[k] = lp[k];

    const f32x4* fb = reinterpret_cast<const f32x4*>(feature)
                      + (size_t)s0 * F4_PER_ROW + lane * 2;
    const f32x4* cbase = reinterpret_cast<const f32x4*>(center);

    float ss[SPW];

    // --- prologue: loads for sample 0 ---
    f32x4 f0c = __builtin_nontemporal_load(fb);
    f32x4 f1c = __builtin_nontemporal_load(fb + 1);
    const f32x4* cp0 = cbase + (size_t)labs[0] * F4_PER_ROW + lane * 2;
    f32x4 c0c = cp0[0];
    f32x4 c1c = cp0[1];

    #pragma unroll
    for (int k = 0; k < SPW; ++k) {
        f32x4 f0n, f1n, c0n, c1n;
        if (k < SPW - 1) {
            const f32x4* fn = fb + (size_t)(k + 1) * F4_PER_ROW;
            f0n = __builtin_nontemporal_load(fn);
            f1n = __builtin_nontemporal_load(fn + 1);
            const f32x4* cn = cbase + (size_t)labs[k + 1] * F4_PER_ROW + lane * 2;
            c0n = cn[0];
            c1n = cn[1];
        }

        float s = 0.0f, d;
        d = f0c.x - c0c.x; s = fmaf(d, d, s);
        d = f0c.y - c0c.y; s = fmaf(d, d, s);
        d = f0c.z - c0c.z; s = fmaf(d, d, s);
        d = f0c.w - c0c.w; s = fmaf(d, d, s);
        d = f1c.x - c1c.x; s = fmaf(d, d, s);
        d = f1c.y - c1c.y; s = fmaf(d, d, s);
        d = f1c.z - c1c.z; s = fmaf(d, d, s);
        d = f1c.w - c1c.w; s = fmaf(d, d, s);
        ss[k] = s;

        if (k < SPW - 1) {
            f0c = f0n; f1c = f1n; c0c = c0n; c1c = c1n;
        }
    }

    // --- batched butterfly: 8 independent 6-step chains, interleaved ---
    #pragma unroll
    for (int off = 32; off > 0; off >>= 1) {
        #pragma unroll
        for (int k = 0; k < SPW; ++k)
            ss[k] += __shfl_xor(ss[k], off, 64);
    }

    if (lane == 0) {
        float a = 0.0f;
        #pragma unroll
        for (int k = 0; k < SPW; ++k) a += sqrtf(ss[k]);
        wsum[wave] = a;
    }
    __syncthreads();
    if (threadIdx.x == 0)
        partial[blockIdx.x] = wsum[0] + wsum[1] + wsum[2] + wsum[3];
}

__global__ __launch_bounds__(BLOCK_THREADS) void center_loss_pass2(
    const float* __restrict__ partial,
    float* __restrict__ out) {
    __shared__ float lds[WAVES_PER_BLOCK];
    const int wave = threadIdx.x >> 6;
    const int lane = threadIdx.x & 63;

    float s = 0.0f;
    for (int i = threadIdx.x; i < GRID_BLOCKS; i += BLOCK_THREADS)
        s += partial[i];

    #pragma unroll
    for (int off = 32; off > 0; off >>= 1)
        s += __shfl_xor(s, off, 64);

    if (lane == 0) lds[wave] = s;
    __syncthreads();
    if (threadIdx.x == 0)
        out[0] = (lds[0] + lds[1] + lds[2] + lds[3]) * (1.0f / (float)N_SAMPLES);
}

extern "C" void kernel_launch(void* const* d_in, const int* in_sizes, int n_in,
                              void* d_out, int out_size, void* d_ws, size_t ws_size,
                              hipStream_t stream) {
    const float* feature = (const float*)d_in[0];
    const int*   label   = (const int*)d_in[1];
    const float* center  = (const float*)d_in[2];
    float* out = (float*)d_out;
    float* partial = (float*)d_ws;  // GRID_BLOCKS floats = 8 KB

    center_loss_pass1<<<GRID_BLOCKS, BLOCK_THREADS, 0, stream>>>(feature, label, center, partial);
    center_loss_pass2<<<1, BLOCK_THREADS, 0, stream>>>(partial, out);
}